// Round 3
// baseline (916.610 us; speedup 1.0000x reference)
//
#include <hip/hip_runtime.h>
#include <hip/hip_bf16.h>
#include <stdint.h>

// ---------------------------------------------------------------------------
// Mlp_cnn_shift: B=2 T=8 H=56 W=56 C=512 HID=1024, N = 50176 tokens
//  xb   = bf16(x)                                   [N,512]
//  GEMM1: xh = gelu(xb@fc_w+b); dual-store: xh + forward-shift scatter -> xs
//  GEMM2: hs = inverse-shift scatter of gelu(xs@fc1_w+b); fused s0 sum
//  GEMM3: w  = gelu(xh@fc2_w+b); fused s1 sum
//  tiny MLP + pairwise softmax -> a0,a1 (fp32 exact)
//  combine: hw = hs*a0 + w*a1 (shift-free, 16B vectorized)
//  GEMM4: out = hw @ proj_w + proj_b (fp32, rounded through bf16 LDS stage)
// All GEMM epilogues stage C through a 32KB XOR-swizzled LDS tile so global
// stores are 16B vectorized (round-2 regression was 128 scalar stores).
// ---------------------------------------------------------------------------

typedef __attribute__((ext_vector_type(8))) short short8;
typedef __attribute__((ext_vector_type(4))) float floatx4;
typedef unsigned int uint;
typedef unsigned short ushort;

#define NTOK   50176
#define HWIMG  3136    // 56*56

__device__ __forceinline__ float gelu_exact(float v) {
    return 0.5f * v * (1.0f + erff(v * 0.70710678118654752440f));
}
// tanh-approx gelu; max abs err ~3e-4, used on the 102.8M big-GEMM activations
__device__ __forceinline__ float gelu_fast(float v) {
    float u = v * (0.7978845608f + 0.0356774081f * v * v);
    return v * __builtin_amdgcn_rcpf(1.0f + __expf(-2.0f * u));
}

// shifts: g in 0..8 -> (1-g/3, 1-g%3) matches SHIFTS table
__device__ __forceinline__ int shift_h(int g) { return 1 - g / 3; }
__device__ __forceinline__ int shift_w(int g) { return 1 - g % 3; }

__device__ __forceinline__ float bf_lo(uint u) { return __uint_as_float(u << 16); }
__device__ __forceinline__ float bf_hi(uint u) { return __uint_as_float(u & 0xffff0000u); }
__device__ __forceinline__ uint pack_bf2(float lo, float hi) {
    __hip_bfloat16 a = __float2bfloat16(lo), b = __float2bfloat16(hi);
    return (uint)*(ushort*)&a | ((uint)*(ushort*)&b << 16);
}

// ---- async global->LDS, 16B per lane ---------------------------------------
typedef const __attribute__((address_space(1))) uint* gas_ptr;
typedef __attribute__((address_space(3))) uint* las_ptr;

__device__ __forceinline__ void async_copy16(const void* g, void* l) {
    gas_ptr gp = (gas_ptr)(uintptr_t)g;
    las_ptr lp = (las_ptr)(uint32_t)(uintptr_t)l;
    __builtin_amdgcn_global_load_lds(gp, lp, 16, 0, 0);
}

// ---- GEMM: C[M,N] = act(A[M,K] @ Bt[N,K]^T + bias) -------------------------
// BM=BN=128, BK=32, 256 thr = 4 waves (2x2), wave 64x64 via 4x4 mfma 16x16x32.
// EPI: 0 = fp32 plain store (GEMM4)
//      1 = gelu bf16 store + forward-shift scatter to Cout2 (GEMM1, N=1024)
//      2 = gelu bf16 inverse-shift scatter ONLY + fused sum -> ssum (GEMM2)
//      3 = gelu bf16 plain store + fused sum -> ssum (GEMM3)
template <int EPI>
__global__ __launch_bounds__(256) void gemm_bt(
    const __hip_bfloat16* __restrict__ A,
    const __hip_bfloat16* __restrict__ Bt,
    const float* __restrict__ bias,
    void* __restrict__ Cout, __hip_bfloat16* __restrict__ Cout2,
    float* __restrict__ ssum, int N, int K)
{
    // union: K-loop staging (16KB) / C-tile staging (32KB, bf16 [128][128] XOR-swizzled)
    __shared__ __align__(16) char smem[32768];
    __hip_bfloat16* As = (__hip_bfloat16*)smem;          // [128][32]
    __hip_bfloat16* Bs = (__hip_bfloat16*)(smem + 8192); // [128][32]
    __hip_bfloat16* Cs = (__hip_bfloat16*)smem;          // [128][128] swizzled

    const int t    = threadIdx.x;
    const int lane = t & 63;
    const int wave = t >> 6;
    const int wm   = wave >> 1;
    const int wn   = wave & 1;

    // XCD swizzle: contiguous bm range per XCD so its private L2 keeps A-tiles
    const int nbn  = gridDim.x;
    const int flat = blockIdx.y * nbn + blockIdx.x;
    const int xcd  = flat & 7;
    const int j    = flat >> 3;
    const int jd   = j / nbn;
    const int bm   = xcd * 49 + jd;
    const int bn   = j - jd * nbn;

    const __hip_bfloat16* ga0 = A  + (size_t)(bm * 128 + (t >> 2)) * K + (t & 3) * 8;
    const __hip_bfloat16* ga1 = ga0 + (size_t)64 * K;
    const __hip_bfloat16* gb0 = Bt + (size_t)(bn * 128 + (t >> 2)) * K + (t & 3) * 8;
    const __hip_bfloat16* gb1 = gb0 + (size_t)64 * K;
    __hip_bfloat16* la0 = &As[t * 8];
    __hip_bfloat16* la1 = &As[t * 8 + 2048];
    __hip_bfloat16* lb0 = &Bs[t * 8];
    __hip_bfloat16* lb1 = &Bs[t * 8 + 2048];

    floatx4 acc[4][4] = {};

    const int kq = (lane >> 4) * 8;
    const int ml = lane & 15;

    for (int k0 = 0; k0 < K; k0 += 32) {
        async_copy16(ga0, la0);
        async_copy16(ga1, la1);
        async_copy16(gb0, lb0);
        async_copy16(gb1, lb1);
        ga0 += 32; ga1 += 32; gb0 += 32; gb1 += 32;
        asm volatile("s_waitcnt vmcnt(0)" ::: "memory");
        __syncthreads();

        short8 af[4], bf[4];
#pragma unroll
        for (int i = 0; i < 4; i++) {
            af[i] = *(const short8*)&As[(wm * 64 + i * 16 + ml) * 32 + kq];
            bf[i] = *(const short8*)&Bs[(wn * 64 + i * 16 + ml) * 32 + kq];
        }
#pragma unroll
        for (int mi = 0; mi < 4; mi++)
#pragma unroll
            for (int ni = 0; ni < 4; ni++)
                acc[mi][ni] = __builtin_amdgcn_mfma_f32_16x16x32_bf16(
                    af[mi], bf[ni], acc[mi][ni], 0, 0, 0);
        __syncthreads();
    }

    // ---- epilogue write phase: bias(+gelu), bf16 -> swizzled LDS tile ------
    // C/D layout: col = lane&15, row = (lane>>4)*4 + reg (m89-verified)
    const int rq = (lane >> 4) * 4;
#pragma unroll
    for (int ni = 0; ni < 4; ni++) {
        const int col = wn * 64 + ni * 16 + ml;
        const float bv = bias[bn * 128 + col];
#pragma unroll
        for (int mi = 0; mi < 4; mi++) {
            const int row0 = wm * 64 + mi * 16 + rq;
#pragma unroll
            for (int r = 0; r < 4; r++) {
                float v = acc[mi][ni][r] + bv;
                if (EPI != 0) v = gelu_fast(v);
                const int rr = row0 + r;
                const int pcol = col ^ (16 * ((rr >> 2) & 3));  // bank swizzle
                Cs[rr * 128 + pcol] = __float2bfloat16(v);
            }
        }
    }
    __syncthreads();

    // ---- epilogue read phase: b128 LDS reads, 16B vectorized global stores -
    const int tcol = (t & 15) * 8;            // local col base (8-chunk)
    const int gc0  = bn * 128 + tcol;         // global col base
    float csum[8] = {};
    int gs_h = 0, gs_w = 0, guni = 1;
    if (EPI == 1) {
        const int g0 = gc0 / 114, g7 = (gc0 + 7) / 114;
        guni = (g0 == g7);
        gs_h = shift_h(g0); gs_w = shift_w(g0);
    } else if (EPI == 2) {
        const int g0 = gc0 / 57, g7 = (gc0 + 7) / 57;
        guni = (g0 == g7);
        gs_h = shift_h(g0); gs_w = shift_w(g0);
    }

#pragma unroll
    for (int i = 0; i < 8; i++) {
        const int lrow = i * 16 + (t >> 4);
        const int tok  = bm * 128 + lrow;
        const int ptcol = tcol ^ (16 * ((lrow >> 2) & 3));
        const uint4 val = *(const uint4*)&Cs[lrow * 128 + ptcol];
        const uint vc[4] = {val.x, val.y, val.z, val.w};

        if (EPI == 0) {
            float4 f0, f1;
            f0.x = bf_lo(vc[0]); f0.y = bf_hi(vc[0]);
            f0.z = bf_lo(vc[1]); f0.w = bf_hi(vc[1]);
            f1.x = bf_lo(vc[2]); f1.y = bf_hi(vc[2]);
            f1.z = bf_lo(vc[3]); f1.w = bf_hi(vc[3]);
            float* op = (float*)Cout + (size_t)tok * N + gc0;
            *(float4*)op = f0;
            *(float4*)(op + 4) = f1;
        } else if (EPI == 3) {
            *(uint4*)((__hip_bfloat16*)Cout + (size_t)tok * N + gc0) = val;
#pragma unroll
            for (int e = 0; e < 4; e++) {
                csum[2 * e]     += bf_lo(vc[e]);
                csum[2 * e + 1] += bf_hi(vc[e]);
            }
        } else {
            // token -> (bt, ph, pw)
            const int bt  = tok / HWIMG;
            const int rem = tok - bt * HWIMG;
            const int ph  = rem / 56;
            const int pw  = rem - ph * 56;
            if (EPI == 1) {
                *(uint4*)((__hip_bfloat16*)Cout + (size_t)tok * 1024 + gc0) = val;
                if (guni) {
                    if ((unsigned)(ph + gs_h) < 56u && (unsigned)(pw + gs_w) < 56u)
                        *(uint4*)(Cout2 + (size_t)(tok + gs_h * 56 + gs_w) * 1024 + gc0) = val;
                } else {
#pragma unroll
                    for (int e = 0; e < 8; e++) {
                        const int c = gc0 + e;
                        const int g = c / 114;
                        const int sh = shift_h(g), sw = shift_w(g);
                        if ((unsigned)(ph + sh) < 56u && (unsigned)(pw + sw) < 56u) {
                            const uint comp = vc[e >> 1];
                            ((ushort*)Cout2)[(size_t)(tok + sh * 56 + sw) * 1024 + c] =
                                (ushort)((e & 1) ? (comp >> 16) : (comp & 0xffffu));
                        }
                    }
                }
            } else { // EPI == 2: inverse-shift scatter + masked sum
                if (guni) {
                    if ((unsigned)(ph - gs_h) < 56u && (unsigned)(pw - gs_w) < 56u) {
                        *(uint4*)((__hip_bfloat16*)Cout +
                                  (size_t)(tok - gs_h * 56 - gs_w) * 512 + gc0) = val;
#pragma unroll
                        for (int e = 0; e < 4; e++) {
                            csum[2 * e]     += bf_lo(vc[e]);
                            csum[2 * e + 1] += bf_hi(vc[e]);
                        }
                    }
                } else {
#pragma unroll
                    for (int e = 0; e < 8; e++) {
                        const int c = gc0 + e;
                        const int g = c / 57;
                        const int sh = shift_h(g), sw = shift_w(g);
                        if ((unsigned)(ph - sh) < 56u && (unsigned)(pw - sw) < 56u) {
                            const uint comp = vc[e >> 1];
                            const ushort us = (ushort)((e & 1) ? (comp >> 16) : (comp & 0xffffu));
                            ((ushort*)Cout)[(size_t)(tok - sh * 56 - sw) * 512 + c] = us;
                            csum[e] += __uint_as_float((uint)us << 16);
                        }
                    }
                }
            }
        }
    }

    if (EPI == 2 || EPI == 3) {
        // lanes sharing t&15 (same cols) sit at lane, lane^16, lane^32, lane^48
#pragma unroll
        for (int e = 0; e < 8; e++) {
            csum[e] += __shfl_xor(csum[e], 16, 64);
            csum[e] += __shfl_xor(csum[e], 32, 64);
        }
        if (lane < 16) {
            const int b = (bm >= 196) ? 1 : 0;   // token 25088 = block 196 boundary
            const int colb = bn * 128 + lane * 8;
#pragma unroll
            for (int e = 0; e < 8; e++)
                atomicAdd(&ssum[b * 512 + colb + e], csum[e]);
        }
    }
}

// ---- zero the shift boundary holes (frame strips only, ~3.5%) --------------
template <int C, int GS, int SGN>
__global__ __launch_bounds__(256) void zero_holes(__hip_bfloat16* __restrict__ buf)
{
    const int i = blockIdx.x * 256 + threadIdx.x;   // 16*220*C exact
    const int c = i % C;
    const int p = i / C;
    const int bt = p / 220, fp = p % 220;
    int oh, ow;
    if (fp < 56)       { oh = 0;        ow = fp; }
    else if (fp < 112) { oh = 55;       ow = fp - 56; }
    else if (fp < 166) { oh = fp - 111; ow = 0; }
    else               { oh = fp - 165; ow = 55; }
    const int g = c / GS;
    const int ih = oh - SGN * shift_h(g);
    const int iw = ow - SGN * shift_w(g);
    if ((unsigned)ih >= 56u || (unsigned)iw >= 56u)
        buf[((size_t)(bt * HWIMG + oh * 56 + ow)) * C + c] = __float2bfloat16(0.0f);
}

// ---- prep: x fp32 -> bf16 ---------------------------------------------------
__global__ __launch_bounds__(256) void cvt_x(const float4* __restrict__ x,
                                             __hip_bfloat16* __restrict__ xb)
{
    int i = blockIdx.x * 256 + threadIdx.x;
    float4 v = x[i];
    uint2 o;
    o.x = pack_bf2(v.x, v.y);
    o.y = pack_bf2(v.z, v.w);
    *(uint2*)&xb[(size_t)i * 4] = o;
}

// ---- prep: transpose + convert the 4 weight matrices to bf16 Bt layout -----
__global__ __launch_bounds__(256) void prep_w(
    const float* __restrict__ fcw,  const float* __restrict__ fc1w,
    const float* __restrict__ fc2w, const float* __restrict__ projw,
    __hip_bfloat16* __restrict__ fcwT, __hip_bfloat16* __restrict__ fc1T,
    __hip_bfloat16* __restrict__ fc2T, __hip_bfloat16* __restrict__ projT)
{
    int i = blockIdx.x * 256 + threadIdx.x;
    if (i < 524288) {                       // fc_w [512,1024] -> [1024,512]
        int n = i >> 9, k = i & 511;
        fcwT[i] = __float2bfloat16(fcw[k * 1024 + n]);
    } else if (i < 1048576) {               // fc1_w [1024,512] -> [512,1024]
        int j = i - 524288;
        int n = j >> 10, k = j & 1023;
        fc1T[j] = __float2bfloat16(fc1w[k * 512 + n]);
    } else if (i < 1572864) {               // fc2_w [1024,512] -> [512,1024]
        int j = i - 1048576;
        int n = j >> 10, k = j & 1023;
        fc2T[j] = __float2bfloat16(fc2w[k * 512 + n]);
    } else if (i < 1835008) {               // proj_w [512,512] -> [512,512]
        int j = i - 1572864;
        int n = j >> 9, k = j & 511;
        projT[j] = __float2bfloat16(projw[k * 512 + n]);
    }
}

// ---- tiny squeeze-excite MLP + pairwise softmax, fp32 exact ----------------
__global__ __launch_bounds__(256) void tiny_mlp(
    const float* __restrict__ s0, const float* __restrict__ s1,
    const float* __restrict__ rw1_w, const float* __restrict__ rw1_b,
    const float* __restrict__ rw2_w, const float* __restrict__ rw2_b,
    float* __restrict__ a0, float* __restrict__ a1)
{
    __shared__ float mean[1024];   // [2][512]
    __shared__ float z[256];       // [2][128]
    __shared__ float av[2048];     // [2][1024]
    const int t = threadIdx.x;
    for (int i = t; i < 1024; i += 256)
        mean[i] = (s0[i] + s1[i]) * (1.0f / 25088.0f);
    __syncthreads();
    {
        const int b = t >> 7, jj = t & 127;
        float acc = rw1_b[jj];
        for (int cc = 0; cc < 512; cc++)
            acc += mean[b * 512 + cc] * rw1_w[cc * 128 + jj];
        z[t] = gelu_exact(acc);
    }
    __syncthreads();
    for (int i = t; i < 2048; i += 256) {
        const int b = i >> 10, o = i & 1023;
        float acc = rw2_b[o];
        for (int jj = 0; jj < 128; jj++)
            acc += z[b * 128 + jj] * rw2_w[jj * 1024 + o];
        av[i] = acc;
    }
    __syncthreads();
    for (int i = t; i < 1024; i += 256) {
        const int b = i >> 9, cc = i & 511;
        const float x0 = av[b * 1024 + 2 * cc];
        const float x1 = av[b * 1024 + 2 * cc + 1];
        const float m = fmaxf(x0, x1);
        const float e0 = expf(x0 - m), e1 = expf(x1 - m);
        const float inv = 1.0f / (e0 + e1);
        a0[i] = e0 * inv;
        a1[i] = e1 * inv;
    }
}

// ---- hw = hs*a0 + w*a1 (shift-free, 8 channels / thread) --------------------
__global__ __launch_bounds__(256) void combine(
    const uint4* __restrict__ hs4, const uint4* __restrict__ w4,
    const float* __restrict__ a0, const float* __restrict__ a1,
    uint4* __restrict__ hw4)
{
    const int i = blockIdx.x * 256 + threadIdx.x;   // 3,211,264 exact
    const int ck = i & 63;                          // 8-channel chunk
    const int tok = i >> 6;
    const int b = (tok >= 25088) ? 1 : 0;
    const float4* A0 = (const float4*)&a0[b * 512 + ck * 8];
    const float4* A1 = (const float4*)&a1[b * 512 + ck * 8];
    const float4 s0l = A0[0], s0h = A0[1];
    const float4 s1l = A1[0], s1h = A1[1];
    const uint4 h = hs4[i], w = w4[i];
    uint4 o;
    o.x = pack_bf2(bf_lo(h.x) * s0l.x + bf_lo(w.x) * s1l.x,
                   bf_hi(h.x) * s0l.y + bf_hi(w.x) * s1l.y);
    o.y = pack_bf2(bf_lo(h.y) * s0l.z + bf_lo(w.y) * s1l.z,
                   bf_hi(h.y) * s0l.w + bf_hi(w.y) * s1l.w);
    o.z = pack_bf2(bf_lo(h.z) * s0h.x + bf_lo(w.z) * s1h.x,
                   bf_hi(h.z) * s0h.y + bf_hi(w.z) * s1h.y);
    o.w = pack_bf2(bf_lo(h.w) * s0h.z + bf_lo(w.w) * s1h.z,
                   bf_hi(h.w) * s0h.w + bf_hi(w.w) * s1h.w);
    hw4[i] = o;
}

// ---------------------------------------------------------------------------
extern "C" void kernel_launch(void* const* d_in, const int* in_sizes, int n_in,
                              void* d_out, int out_size, void* d_ws, size_t ws_size,
                              hipStream_t stream)
{
    const float* x      = (const float*)d_in[0];
    const float* fc_w   = (const float*)d_in[1];
    const float* fc_b   = (const float*)d_in[2];
    const float* fc1_w  = (const float*)d_in[3];
    const float* fc1_b  = (const float*)d_in[4];
    const float* fc2_w  = (const float*)d_in[5];
    const float* fc2_b  = (const float*)d_in[6];
    const float* rw1_w  = (const float*)d_in[7];
    const float* rw1_b  = (const float*)d_in[8];
    const float* rw2_w  = (const float*)d_in[9];
    const float* rw2_b  = (const float*)d_in[10];
    const float* proj_w = (const float*)d_in[11];
    const float* proj_b = (const float*)d_in[12];

    uint8_t* ws = (uint8_t*)d_ws;
    __hip_bfloat16* xh  = (__hip_bfloat16*)(ws);                    // [N,1024] bf16, later hw
    __hip_bfloat16* xb  = (__hip_bfloat16*)(ws + 102760448);        // [N,512] bf16, later hs
    uint8_t* wt         = ws + 102760448 + 51380224;
    __hip_bfloat16* fcwT  = (__hip_bfloat16*)(wt);
    __hip_bfloat16* fc1T  = fcwT + 524288;
    __hip_bfloat16* fc2T  = fc1T + 524288;
    __hip_bfloat16* projT = fc2T + 524288;
    float* s0 = (float*)(wt + 3670016);
    float* s1 = s0 + 1024;
    float* a0 = s1 + 1024;
    float* a1 = a0 + 1024;

    __hip_bfloat16* xs   = (__hip_bfloat16*)d_out;  // [N,1024] bf16 (dead after GEMM2)
    __hip_bfloat16* wbuf = (__hip_bfloat16*)d_out;  // [N,512]  bf16 (dead after combine)
    __hip_bfloat16* hs   = xb;                      // [N,512]  bf16 (xb dead after GEMM1)
    __hip_bfloat16* hw   = xh;                      // [N,512]  bf16 (xh dead after GEMM3)

    hipMemsetAsync(s0, 0, 8192, stream);            // zero s0,s1

    // xs boundary holes (d_out, no deps) — before GEMM1's scatter fills valid cells
    zero_holes<1024, 114, +1><<<14080, 256, 0, stream>>>(xs);
    cvt_x<<<25088, 256, 0, stream>>>((const float4*)x, xb);
    prep_w<<<7168, 256, 0, stream>>>(fc_w, fc1_w, fc2_w, proj_w, fcwT, fc1T, fc2T, projT);

    // GEMM1: xh = gelu(xb@fc_w+b); dual store xh + fwd-shift scatter -> xs
    gemm_bt<1><<<dim3(8, 392), 256, 0, stream>>>(xb, fcwT, fc_b, xh, xs, nullptr, 1024, 512);
    // hs boundary holes (hs aliases xb -> must run after GEMM1)
    zero_holes<512, 57, -1><<<7040, 256, 0, stream>>>(hs);
    // GEMM2: hs = inv-shift scatter of gelu(xs@fc1_w+b); fused s0
    gemm_bt<2><<<dim3(4, 392), 256, 0, stream>>>(xs, fc1T, fc1_b, hs, nullptr, s0, 512, 1024);
    // GEMM3: w = gelu(xh@fc2_w+b) -> d_out (xs dead); fused s1
    gemm_bt<3><<<dim3(4, 392), 256, 0, stream>>>(xh, fc2T, fc2_b, wbuf, nullptr, s1, 512, 1024);
    // tiny MLP + softmax -> a0,a1
    tiny_mlp<<<1, 256, 0, stream>>>(s0, s1, rw1_w, rw1_b, rw2_w, rw2_b, a0, a1);
    // hw = hs*a0 + w*a1 -> xh region
    combine<<<12544, 256, 0, stream>>>((const uint4*)hs, (const uint4*)wbuf, a0, a1, (uint4*)hw);
    // GEMM4: out = hw @ proj_w + proj_b, fp32 -> d_out
    gemm_bt<0><<<dim3(4, 392), 256, 0, stream>>>(hw, projT, proj_b, d_out, nullptr, nullptr, 512, 512);
}

// Round 4
// 742.243 us; speedup vs baseline: 1.2349x; 1.2349x over previous
//
#include <hip/hip_runtime.h>
#include <hip/hip_bf16.h>
#include <stdint.h>

// ---------------------------------------------------------------------------
// Mlp_cnn_shift: B=2 T=8 H=56 W=56 C=512 HID=1024, N = 50176 tokens
//  xb   = bf16(x)                                   [N,512]
//  GEMM1: xh = gelu(xb@fc_w+b); dual-store: xh + forward-shift scatter -> xs
//  GEMM2: hpre = gelu(xs@fc1_w+b) plain store; fused masked s0 sum
//  GEMM3: w  = gelu(xh@fc2_w+b); fused s1 sum
//  tiny MLP + pairwise softmax -> a0,a1 (fp32 exact)
//  combine: hw = inv_shift(hpre)*a0 + w*a1 (shift applied on load)
//  GEMM4: out = hw @ proj_w + proj_b (fp32)
// GEMM uses OPERAND-SWAPPED MFMA (a-frag=weights, b-frag=tokens) so each lane
// owns 4 consecutive CHANNELS of one token -> 8B/16B vector stores in-register
// (round-3's LDS-staged epilogue serialized on barriers; round-1/2's layout
// forced scalar stores).
// ---------------------------------------------------------------------------

typedef __attribute__((ext_vector_type(8))) short short8;
typedef __attribute__((ext_vector_type(4))) float floatx4;
typedef unsigned int uint;
typedef unsigned short ushort;

#define NTOK   50176
#define HWIMG  3136    // 56*56

__device__ __forceinline__ float gelu_exact(float v) {
    return 0.5f * v * (1.0f + erff(v * 0.70710678118654752440f));
}
// tanh-approx gelu; max abs err ~3e-4, used on the 102.8M big-GEMM activations
__device__ __forceinline__ float gelu_fast(float v) {
    float u = v * (0.7978845608f + 0.0356774081f * v * v);
    return v * __builtin_amdgcn_rcpf(1.0f + __expf(-2.0f * u));
}

// shifts: g in 0..8 -> (1-g/3, 1-g%3) matches SHIFTS table
__device__ __forceinline__ int shift_h(int g) { return 1 - g / 3; }
__device__ __forceinline__ int shift_w(int g) { return 1 - g % 3; }

__device__ __forceinline__ float bf_lo(uint u) { return __uint_as_float(u << 16); }
__device__ __forceinline__ float bf_hi(uint u) { return __uint_as_float(u & 0xffff0000u); }
__device__ __forceinline__ uint pack_bf2(float lo, float hi) {
    __hip_bfloat16 a = __float2bfloat16(lo), b = __float2bfloat16(hi);
    return (uint)*(ushort*)&a | ((uint)*(ushort*)&b << 16);
}

// ---- async global->LDS, 16B per lane ---------------------------------------
typedef const __attribute__((address_space(1))) uint* gas_ptr;
typedef __attribute__((address_space(3))) uint* las_ptr;

__device__ __forceinline__ void async_copy16(const void* g, void* l) {
    gas_ptr gp = (gas_ptr)(uintptr_t)g;
    las_ptr lp = (las_ptr)(uint32_t)(uintptr_t)l;
    __builtin_amdgcn_global_load_lds(gp, lp, 16, 0, 0);
}

// ---- GEMM: C[M,N] = act(A[M,K] @ Bt[N,K]^T + bias) -------------------------
// BM=BN=128, BK=32, 256 thr = 4 waves (2x2), wave = 64 ch x 64 tok.
// MFMA operands swapped: acc[ci][ti] = mfma(wfrag[ci], tfrag[ti], .) ->
// D row (quad*4+reg) = channel, D col (lane&15) = token.
// EPI: 0 = fp32 dwordx4 store (GEMM4)
//      1 = gelu bf16 store + forward-shift scatter to Cout2 (GEMM1, N=1024)
//      2 = gelu bf16 plain store + MASKED sum -> ssum (GEMM2, group=57)
//      3 = gelu bf16 plain store + sum -> ssum (GEMM3)
template <int EPI>
__global__ __launch_bounds__(256) void gemm_bt(
    const __hip_bfloat16* __restrict__ A,
    const __hip_bfloat16* __restrict__ Bt,
    const float* __restrict__ bias,
    void* __restrict__ Cout, __hip_bfloat16* __restrict__ Cout2,
    float* __restrict__ ssum, int N, int K)
{
    __shared__ __hip_bfloat16 As[128 * 32];
    __shared__ __hip_bfloat16 Bs[128 * 32];

    const int t    = threadIdx.x;
    const int lane = t & 63;
    const int wave = t >> 6;
    const int wm   = wave >> 1;   // token half
    const int wn   = wave & 1;    // channel half

    // XCD swizzle: contiguous bm range per XCD so its private L2 keeps A-tiles
    const int nbn  = gridDim.x;
    const int flat = blockIdx.y * nbn + blockIdx.x;
    const int xcd  = flat & 7;
    const int j    = flat >> 3;
    const int jd   = j / nbn;
    const int bm   = xcd * 49 + jd;
    const int bn   = j - jd * nbn;

    const __hip_bfloat16* ga0 = A  + (size_t)(bm * 128 + (t >> 2)) * K + (t & 3) * 8;
    const __hip_bfloat16* ga1 = ga0 + (size_t)64 * K;
    const __hip_bfloat16* gb0 = Bt + (size_t)(bn * 128 + (t >> 2)) * K + (t & 3) * 8;
    const __hip_bfloat16* gb1 = gb0 + (size_t)64 * K;
    __hip_bfloat16* la0 = &As[t * 8];
    __hip_bfloat16* la1 = &As[t * 8 + 2048];
    __hip_bfloat16* lb0 = &Bs[t * 8];
    __hip_bfloat16* lb1 = &Bs[t * 8 + 2048];

    floatx4 acc[4][4] = {};   // [ci][ti]

    const int kq = (lane >> 4) * 8;
    const int ml = lane & 15;

    for (int k0 = 0; k0 < K; k0 += 32) {
        async_copy16(ga0, la0);
        async_copy16(ga1, la1);
        async_copy16(gb0, lb0);
        async_copy16(gb1, lb1);
        ga0 += 32; ga1 += 32; gb0 += 32; gb1 += 32;
        asm volatile("s_waitcnt vmcnt(0)" ::: "memory");
        __syncthreads();

        short8 wf[4], tf[4];
#pragma unroll
        for (int i = 0; i < 4; i++) {
            wf[i] = *(const short8*)&Bs[(wn * 64 + i * 16 + ml) * 32 + kq];
            tf[i] = *(const short8*)&As[(wm * 64 + i * 16 + ml) * 32 + kq];
        }
#pragma unroll
        for (int ci = 0; ci < 4; ci++)
#pragma unroll
            for (int ti = 0; ti < 4; ti++)
                acc[ci][ti] = __builtin_amdgcn_mfma_f32_16x16x32_bf16(
                    wf[ci], tf[ti], acc[ci][ti], 0, 0, 0);
        __syncthreads();
    }

    // ---- epilogue: lane owns channels ch0..ch0+3 (contiguous) of one token -
    const int rq   = (lane >> 4) * 4;
    const int chB  = bn * 128 + wn * 64;      // wave channel base
    const int tokB = bm * 128 + wm * 64;      // wave token base

    float4 bias4[4];
    int g0c[4], g3c[4];
#pragma unroll
    for (int ci = 0; ci < 4; ci++) {
        const int ch0 = chB + ci * 16 + rq;
        bias4[ci] = *(const float4*)&bias[ch0];
        if (EPI == 1) { g0c[ci] = ch0 / 114; g3c[ci] = (ch0 + 3) / 114; }
        if (EPI == 2) { g0c[ci] = ch0 / 57;  g3c[ci] = (ch0 + 3) / 57;  }
    }

    float csum[4][4] = {};   // [ci][r] per-channel partial sums (EPI 2,3)

#pragma unroll
    for (int ti = 0; ti < 4; ti++) {
        const int tok = tokB + ti * 16 + ml;
        int ph = 0, pw = 0;
        if (EPI == 1 || EPI == 2) {
            const int bt  = tok / HWIMG;
            const int rem = tok - bt * HWIMG;
            ph = rem / 56;
            pw = rem - ph * 56;
        }
#pragma unroll
        for (int ci = 0; ci < 4; ci++) {
            const int ch0 = chB + ci * 16 + rq;
            float v[4];
#pragma unroll
            for (int r = 0; r < 4; r++) {
                float x = acc[ci][ti][r] + ((const float*)&bias4[ci])[r];
                v[r] = (EPI != 0) ? gelu_fast(x) : x;
            }
            if (EPI == 0) {
                float4 o; o.x = v[0]; o.y = v[1]; o.z = v[2]; o.w = v[3];
                *(float4*)((float*)Cout + (size_t)tok * N + ch0) = o;
            } else {
                const uint u0 = pack_bf2(v[0], v[1]);
                const uint u1 = pack_bf2(v[2], v[3]);
                uint2 uu; uu.x = u0; uu.y = u1;
                if (EPI != 2 || true)  // EPI 1,2,3 all store plain output
                    *(uint2*)((__hip_bfloat16*)Cout + (size_t)tok * N + ch0) = uu;
                if (EPI == 1) {
                    // forward-shift scatter: xs[tok+s] = xh[tok]
                    if (g0c[ci] == g3c[ci]) {
                        const int sh = shift_h(g0c[ci]), sw = shift_w(g0c[ci]);
                        if ((unsigned)(ph + sh) < 56u && (unsigned)(pw + sw) < 56u)
                            *(uint2*)(Cout2 + (size_t)(tok + sh * 56 + sw) * N + ch0) = uu;
                    } else {
                        // 114 even -> each uint (2ch) uniform
                        const int gA = ch0 / 114, gB = (ch0 + 2) / 114;
                        const int shA = shift_h(gA), swA = shift_w(gA);
                        const int shB = shift_h(gB), swB = shift_w(gB);
                        if ((unsigned)(ph + shA) < 56u && (unsigned)(pw + swA) < 56u)
                            *(uint*)(Cout2 + (size_t)(tok + shA * 56 + swA) * N + ch0) = u0;
                        if ((unsigned)(ph + shB) < 56u && (unsigned)(pw + swB) < 56u)
                            *(uint*)(Cout2 + (size_t)(tok + shB * 56 + swB) * N + ch0 + 2) = u1;
                    }
                } else if (EPI == 2) {
                    // masked sum: hpre[p] counts iff (p - s) is a valid output pos
                    if (g0c[ci] == g3c[ci]) {
                        const int sh = shift_h(g0c[ci]), sw = shift_w(g0c[ci]);
                        if ((unsigned)(ph - sh) < 56u && (unsigned)(pw - sw) < 56u) {
#pragma unroll
                            for (int r = 0; r < 4; r++) csum[ci][r] += v[r];
                        }
                    } else {
#pragma unroll
                        for (int r = 0; r < 4; r++) {
                            const int g = (ch0 + r) / 57;
                            const int sh = shift_h(g), sw = shift_w(g);
                            if ((unsigned)(ph - sh) < 56u && (unsigned)(pw - sw) < 56u)
                                csum[ci][r] += v[r];
                        }
                    }
                } else if (EPI == 3) {
#pragma unroll
                    for (int r = 0; r < 4; r++) csum[ci][r] += v[r];
                }
            }
        }
    }

    if (EPI == 2 || EPI == 3) {
        const int b = (bm >= 196) ? 1 : 0;   // token 25088 = block 196 boundary
#pragma unroll
        for (int ci = 0; ci < 4; ci++) {
#pragma unroll
            for (int r = 0; r < 4; r++) {
                float s = csum[ci][r];
                s += __shfl_xor(s, 1, 64);
                s += __shfl_xor(s, 2, 64);
                s += __shfl_xor(s, 4, 64);
                s += __shfl_xor(s, 8, 64);
                if (ml == 0)
                    atomicAdd(&ssum[b * 512 + chB + ci * 16 + rq + r], s);
            }
        }
    }
}

// ---- zero the shift boundary holes of xs (frame strips only, ~3.5%) --------
template <int C, int GS, int SGN>
__global__ __launch_bounds__(256) void zero_holes(__hip_bfloat16* __restrict__ buf)
{
    const int i = blockIdx.x * 256 + threadIdx.x;   // 16*220*C exact
    const int c = i % C;
    const int p = i / C;
    const int bt = p / 220, fp = p % 220;
    int oh, ow;
    if (fp < 56)       { oh = 0;        ow = fp; }
    else if (fp < 112) { oh = 55;       ow = fp - 56; }
    else if (fp < 166) { oh = fp - 111; ow = 0; }
    else               { oh = fp - 165; ow = 55; }
    const int g = c / GS;
    const int ih = oh - SGN * shift_h(g);
    const int iw = ow - SGN * shift_w(g);
    if ((unsigned)ih >= 56u || (unsigned)iw >= 56u)
        buf[((size_t)(bt * HWIMG + oh * 56 + ow)) * C + c] = __float2bfloat16(0.0f);
}

// ---- prep: x fp32 -> bf16 ---------------------------------------------------
__global__ __launch_bounds__(256) void cvt_x(const float4* __restrict__ x,
                                             __hip_bfloat16* __restrict__ xb)
{
    int i = blockIdx.x * 256 + threadIdx.x;
    float4 v = x[i];
    uint2 o;
    o.x = pack_bf2(v.x, v.y);
    o.y = pack_bf2(v.z, v.w);
    *(uint2*)&xb[(size_t)i * 4] = o;
}

// ---- prep: transpose + convert the 4 weight matrices to bf16 Bt layout -----
__global__ __launch_bounds__(256) void prep_w(
    const float* __restrict__ fcw,  const float* __restrict__ fc1w,
    const float* __restrict__ fc2w, const float* __restrict__ projw,
    __hip_bfloat16* __restrict__ fcwT, __hip_bfloat16* __restrict__ fc1T,
    __hip_bfloat16* __restrict__ fc2T, __hip_bfloat16* __restrict__ projT)
{
    int i = blockIdx.x * 256 + threadIdx.x;
    if (i < 524288) {                       // fc_w [512,1024] -> [1024,512]
        int n = i >> 9, k = i & 511;
        fcwT[i] = __float2bfloat16(fcw[k * 1024 + n]);
    } else if (i < 1048576) {               // fc1_w [1024,512] -> [512,1024]
        int j = i - 524288;
        int n = j >> 10, k = j & 1023;
        fc1T[j] = __float2bfloat16(fc1w[k * 512 + n]);
    } else if (i < 1572864) {               // fc2_w [1024,512] -> [512,1024]
        int j = i - 1048576;
        int n = j >> 10, k = j & 1023;
        fc2T[j] = __float2bfloat16(fc2w[k * 512 + n]);
    } else if (i < 1835008) {               // proj_w [512,512] -> [512,512]
        int j = i - 1572864;
        int n = j >> 9, k = j & 511;
        projT[j] = __float2bfloat16(projw[k * 512 + n]);
    }
}

// ---- tiny squeeze-excite MLP + pairwise softmax, fp32 exact ----------------
__global__ __launch_bounds__(256) void tiny_mlp(
    const float* __restrict__ s0, const float* __restrict__ s1,
    const float* __restrict__ rw1_w, const float* __restrict__ rw1_b,
    const float* __restrict__ rw2_w, const float* __restrict__ rw2_b,
    float* __restrict__ a0, float* __restrict__ a1)
{
    __shared__ float mean[1024];   // [2][512]
    __shared__ float z[256];       // [2][128]
    __shared__ float av[2048];     // [2][1024]
    const int t = threadIdx.x;
    for (int i = t; i < 1024; i += 256)
        mean[i] = (s0[i] + s1[i]) * (1.0f / 25088.0f);
    __syncthreads();
    {
        const int b = t >> 7, jj = t & 127;
        float acc = rw1_b[jj];
        for (int cc = 0; cc < 512; cc++)
            acc += mean[b * 512 + cc] * rw1_w[cc * 128 + jj];
        z[t] = gelu_exact(acc);
    }
    __syncthreads();
    for (int i = t; i < 2048; i += 256) {
        const int b = i >> 10, o = i & 1023;
        float acc = rw2_b[o];
        for (int jj = 0; jj < 128; jj++)
            acc += z[b * 128 + jj] * rw2_w[jj * 1024 + o];
        av[i] = acc;
    }
    __syncthreads();
    for (int i = t; i < 1024; i += 256) {
        const int b = i >> 9, cc = i & 511;
        const float x0 = av[b * 1024 + 2 * cc];
        const float x1 = av[b * 1024 + 2 * cc + 1];
        const float m = fmaxf(x0, x1);
        const float e0 = expf(x0 - m), e1 = expf(x1 - m);
        const float inv = 1.0f / (e0 + e1);
        a0[i] = e0 * inv;
        a1[i] = e1 * inv;
    }
}

// ---- combine: hw = inv_shift(hpre)*a0 + w*a1 (shift applied on load) -------
__global__ __launch_bounds__(256) void combine(
    const __hip_bfloat16* __restrict__ hpre, const uint4* __restrict__ w4,
    const float* __restrict__ a0, const float* __restrict__ a1,
    uint4* __restrict__ hw4)
{
    const int i = blockIdx.x * 256 + threadIdx.x;   // 3,211,264 exact
    const int ck = i & 63;                          // 8-channel chunk
    const int tok = i >> 6;
    const int b = (tok >= 25088) ? 1 : 0;
    const int c0 = ck * 8;
    const int bt  = tok / HWIMG;
    const int rem = tok - bt * HWIMG;
    const int ph  = rem / 56;
    const int pw  = rem - ph * 56;

    float h[8];
    const int g0 = c0 / 57, g7 = (c0 + 7) / 57;
    if (g0 == g7) {
        const int sh = shift_h(g0), sw = shift_w(g0);
        if ((unsigned)(ph + sh) < 56u && (unsigned)(pw + sw) < 56u) {
            const uint4 hv = *(const uint4*)&hpre[(size_t)(tok + sh * 56 + sw) * 512 + c0];
            h[0] = bf_lo(hv.x); h[1] = bf_hi(hv.x);
            h[2] = bf_lo(hv.y); h[3] = bf_hi(hv.y);
            h[4] = bf_lo(hv.z); h[5] = bf_hi(hv.z);
            h[6] = bf_lo(hv.w); h[7] = bf_hi(hv.w);
        } else {
#pragma unroll
            for (int e = 0; e < 8; e++) h[e] = 0.f;
        }
    } else {
#pragma unroll
        for (int e = 0; e < 8; e++) {
            const int g = (c0 + e) / 57;
            const int sh = shift_h(g), sw = shift_w(g);
            h[e] = ((unsigned)(ph + sh) < 56u && (unsigned)(pw + sw) < 56u)
                 ? (float)hpre[(size_t)(tok + sh * 56 + sw) * 512 + c0 + e] : 0.f;
        }
    }

    const float4* A0 = (const float4*)&a0[b * 512 + c0];
    const float4* A1 = (const float4*)&a1[b * 512 + c0];
    const float4 s0l = A0[0], s0h = A0[1];
    const float4 s1l = A1[0], s1h = A1[1];
    const uint4 w = w4[i];
    uint4 o;
    o.x = pack_bf2(h[0] * s0l.x + bf_lo(w.x) * s1l.x,
                   h[1] * s0l.y + bf_hi(w.x) * s1l.y);
    o.y = pack_bf2(h[2] * s0l.z + bf_lo(w.y) * s1l.z,
                   h[3] * s0l.w + bf_hi(w.y) * s1l.w);
    o.z = pack_bf2(h[4] * s0h.x + bf_lo(w.z) * s1h.x,
                   h[5] * s0h.y + bf_hi(w.z) * s1h.y);
    o.w = pack_bf2(h[6] * s0h.z + bf_lo(w.w) * s1h.z,
                   h[7] * s0h.w + bf_hi(w.w) * s1h.w);
    hw4[i] = o;
}

// ---------------------------------------------------------------------------
extern "C" void kernel_launch(void* const* d_in, const int* in_sizes, int n_in,
                              void* d_out, int out_size, void* d_ws, size_t ws_size,
                              hipStream_t stream)
{
    const float* x      = (const float*)d_in[0];
    const float* fc_w   = (const float*)d_in[1];
    const float* fc_b   = (const float*)d_in[2];
    const float* fc1_w  = (const float*)d_in[3];
    const float* fc1_b  = (const float*)d_in[4];
    const float* fc2_w  = (const float*)d_in[5];
    const float* fc2_b  = (const float*)d_in[6];
    const float* rw1_w  = (const float*)d_in[7];
    const float* rw1_b  = (const float*)d_in[8];
    const float* rw2_w  = (const float*)d_in[9];
    const float* rw2_b  = (const float*)d_in[10];
    const float* proj_w = (const float*)d_in[11];
    const float* proj_b = (const float*)d_in[12];

    uint8_t* ws = (uint8_t*)d_ws;
    __hip_bfloat16* xh  = (__hip_bfloat16*)(ws);                    // [N,1024] bf16, later hw
    __hip_bfloat16* xb  = (__hip_bfloat16*)(ws + 102760448);        // [N,512] bf16, later hpre
    uint8_t* wt         = ws + 102760448 + 51380224;
    __hip_bfloat16* fcwT  = (__hip_bfloat16*)(wt);
    __hip_bfloat16* fc1T  = fcwT + 524288;
    __hip_bfloat16* fc2T  = fc1T + 524288;
    __hip_bfloat16* projT = fc2T + 524288;
    float* s0 = (float*)(wt + 3670016);
    float* s1 = s0 + 1024;
    float* a0 = s1 + 1024;
    float* a1 = a0 + 1024;

    __hip_bfloat16* xs   = (__hip_bfloat16*)d_out;  // [N,1024] bf16 (dead after GEMM2)
    __hip_bfloat16* wbuf = (__hip_bfloat16*)d_out;  // [N,512]  bf16 (dead after combine)
    __hip_bfloat16* hpre = xb;                      // [N,512]  bf16 (xb dead after GEMM1)
    __hip_bfloat16* hw   = xh;                      // [N,512]  bf16 (xh dead after GEMM3)

    hipMemsetAsync(s0, 0, 8192, stream);            // zero s0,s1

    // xs boundary holes (d_out, no deps) — before GEMM1's scatter fills valid cells
    zero_holes<1024, 114, +1><<<14080, 256, 0, stream>>>(xs);
    cvt_x<<<25088, 256, 0, stream>>>((const float4*)x, xb);
    prep_w<<<7168, 256, 0, stream>>>(fc_w, fc1_w, fc2_w, proj_w, fcwT, fc1T, fc2T, projT);

    // GEMM1: xh = gelu(xb@fc_w+b); dual store xh + fwd-shift scatter -> xs
    gemm_bt<1><<<dim3(8, 392), 256, 0, stream>>>(xb, fcwT, fc_b, xh, xs, nullptr, 1024, 512);
    // GEMM2: hpre = gelu(xs@fc1_w+b) plain; fused masked s0
    gemm_bt<2><<<dim3(4, 392), 256, 0, stream>>>(xs, fc1T, fc1_b, hpre, nullptr, s0, 512, 1024);
    // GEMM3: w = gelu(xh@fc2_w+b) -> d_out (xs dead); fused s1
    gemm_bt<3><<<dim3(4, 392), 256, 0, stream>>>(xh, fc2T, fc2_b, wbuf, nullptr, s1, 512, 1024);
    // tiny MLP + softmax -> a0,a1
    tiny_mlp<<<1, 256, 0, stream>>>(s0, s1, rw1_w, rw1_b, rw2_w, rw2_b, a0, a1);
    // hw = inv_shift(hpre)*a0 + w*a1 -> xh region
    combine<<<12544, 256, 0, stream>>>(hpre, (const uint4*)wbuf, a0, a1, (uint4*)hw);
    // GEMM4: out = hw @ proj_w + proj_b, fp32 -> d_out
    gemm_bt<0><<<dim3(4, 392), 256, 0, stream>>>(hw, projT, proj_b, d_out, nullptr, nullptr, 512, 512);
}

// Round 5
// 670.426 us; speedup vs baseline: 1.3672x; 1.1071x over previous
//
#include <hip/hip_runtime.h>
#include <hip/hip_bf16.h>
#include <stdint.h>

// ---------------------------------------------------------------------------
// Mlp_cnn_shift: B=2 T=8 H=56 W=56 C=512 HID=1024, N = 50176 tokens
//  xb   = bf16(x)                                   [N,512]
//  GEMM1: xh = gelu(xb@fc_w+b); dual-store: xh + forward-shift scatter -> xs
//  GEMM2: hpre = gelu(xs@fc1_w+b) plain store; fused masked s0 sum
//  GEMM3: w  = gelu(xh@fc2_w+b); fused s1 sum
//  tiny MLP + pairwise softmax -> a0,a1 (fp32 exact)
//  combine: hw = inv_shift(hpre)*a0 + w*a1 (shift applied on load)
//  GEMM4: out = hw @ proj_w + proj_b (fp32)
// GEMM K-loop is DOUBLE-BUFFERED: tile k+1's global_load_lds issued before
// waiting vmcnt(4) on tile k; raw s_barrier (NOT __syncthreads, which drains
// vmcnt(0) and defeats the prefetch). Epilogue is the operand-swapped MFMA
// layout (lane owns 4 consecutive channels of one token -> vector stores).
// ---------------------------------------------------------------------------

typedef __attribute__((ext_vector_type(8))) short short8;
typedef __attribute__((ext_vector_type(4))) float floatx4;
typedef unsigned int uint;
typedef unsigned short ushort;

#define NTOK   50176
#define HWIMG  3136    // 56*56

__device__ __forceinline__ float gelu_exact(float v) {
    return 0.5f * v * (1.0f + erff(v * 0.70710678118654752440f));
}
// tanh-approx gelu; max abs err ~3e-4, used on the 102.8M big-GEMM activations
__device__ __forceinline__ float gelu_fast(float v) {
    float u = v * (0.7978845608f + 0.0356774081f * v * v);
    return v * __builtin_amdgcn_rcpf(1.0f + __expf(-2.0f * u));
}

// shifts: g in 0..8 -> (1-g/3, 1-g%3) matches SHIFTS table
__device__ __forceinline__ int shift_h(int g) { return 1 - g / 3; }
__device__ __forceinline__ int shift_w(int g) { return 1 - g % 3; }

__device__ __forceinline__ float bf_lo(uint u) { return __uint_as_float(u << 16); }
__device__ __forceinline__ float bf_hi(uint u) { return __uint_as_float(u & 0xffff0000u); }
__device__ __forceinline__ uint pack_bf2(float lo, float hi) {
    __hip_bfloat16 a = __float2bfloat16(lo), b = __float2bfloat16(hi);
    return (uint)*(ushort*)&a | ((uint)*(ushort*)&b << 16);
}

// ---- async global->LDS, 16B per lane ---------------------------------------
typedef const __attribute__((address_space(1))) uint* gas_ptr;
typedef __attribute__((address_space(3))) uint* las_ptr;

__device__ __forceinline__ void async_copy16(const void* g, void* l) {
    gas_ptr gp = (gas_ptr)(uintptr_t)g;
    las_ptr lp = (las_ptr)(uint32_t)(uintptr_t)l;
    __builtin_amdgcn_global_load_lds(gp, lp, 16, 0, 0);
}

// ---- GEMM: C[M,N] = act(A[M,K] @ Bt[N,K]^T + bias) -------------------------
// BM=BN=128, BK=32, 256 thr = 4 waves (2x2), wave = 64 ch x 64 tok.
// MFMA operands swapped: acc[ci][ti] = mfma(wfrag[ci], tfrag[ti], .) ->
// D row (quad*4+reg) = channel, D col (lane&15) = token.
// EPI: 0 = fp32 dwordx4 store (GEMM4)
//      1 = gelu bf16 store + forward-shift scatter to Cout2 (GEMM1, N=1024)
//      2 = gelu bf16 plain store + MASKED sum -> ssum (GEMM2, group=57)
//      3 = gelu bf16 plain store + sum -> ssum (GEMM3)
template <int EPI>
__global__ __launch_bounds__(256) void gemm_bt(
    const __hip_bfloat16* __restrict__ A,
    const __hip_bfloat16* __restrict__ Bt,
    const float* __restrict__ bias,
    void* __restrict__ Cout, __hip_bfloat16* __restrict__ Cout2,
    float* __restrict__ ssum, int N, int K)
{
    __shared__ __hip_bfloat16 As[2 * 128 * 32];   // double-buffered
    __shared__ __hip_bfloat16 Bs[2 * 128 * 32];

    const int t    = threadIdx.x;
    const int lane = t & 63;
    const int wave = t >> 6;
    const int wm   = wave >> 1;   // token half
    const int wn   = wave & 1;    // channel half

    // XCD swizzle: contiguous bm range per XCD so its private L2 keeps A-tiles
    const int nbn  = gridDim.x;
    const int flat = blockIdx.y * nbn + blockIdx.x;
    const int xcd  = flat & 7;
    const int j    = flat >> 3;
    const int jd   = j / nbn;
    const int bm   = xcd * 49 + jd;
    const int bn   = j - jd * nbn;

    const __hip_bfloat16* ga0 = A  + (size_t)(bm * 128 + (t >> 2)) * K + (t & 3) * 8;
    const __hip_bfloat16* ga1 = ga0 + (size_t)64 * K;
    const __hip_bfloat16* gb0 = Bt + (size_t)(bn * 128 + (t >> 2)) * K + (t & 3) * 8;
    const __hip_bfloat16* gb1 = gb0 + (size_t)64 * K;
    __hip_bfloat16* la0 = &As[t * 8];
    __hip_bfloat16* la1 = &As[t * 8 + 2048];
    __hip_bfloat16* lb0 = &Bs[t * 8];
    __hip_bfloat16* lb1 = &Bs[t * 8 + 2048];

    floatx4 acc[4][4] = {};   // [ci][ti]

    const int kq = (lane >> 4) * 8;
    const int ml = lane & 15;
    const int iters = K >> 5;

    // prologue: tile 0 -> buffer 0
    async_copy16(ga0, la0);
    async_copy16(ga1, la1);
    async_copy16(gb0, lb0);
    async_copy16(gb1, lb1);
    ga0 += 32; ga1 += 32; gb0 += 32; gb1 += 32;

    for (int k = 0; k < iters; ++k) {
        const int cur = k & 1;
        if (k + 1 < iters) {
            // prefetch tile k+1 into the other buffer, keep it in flight
            const int off = (cur ^ 1) * 4096;
            async_copy16(ga0, la0 + off);
            async_copy16(ga1, la1 + off);
            async_copy16(gb0, lb0 + off);
            async_copy16(gb1, lb1 + off);
            ga0 += 32; ga1 += 32; gb0 += 32; gb1 += 32;
            asm volatile("s_waitcnt vmcnt(4)" ::: "memory");   // tile k done
        } else {
            asm volatile("s_waitcnt vmcnt(0)" ::: "memory");
        }
        asm volatile("s_barrier" ::: "memory");   // raw: no vmcnt(0) drain

        const __hip_bfloat16* Ab = As + cur * 4096;
        const __hip_bfloat16* Bb = Bs + cur * 4096;
        short8 wf[4], tf[4];
#pragma unroll
        for (int i = 0; i < 4; i++) {
            wf[i] = *(const short8*)&Bb[(wn * 64 + i * 16 + ml) * 32 + kq];
            tf[i] = *(const short8*)&Ab[(wm * 64 + i * 16 + ml) * 32 + kq];
        }
#pragma unroll
        for (int ci = 0; ci < 4; ci++)
#pragma unroll
            for (int ti = 0; ti < 4; ti++)
                acc[ci][ti] = __builtin_amdgcn_mfma_f32_16x16x32_bf16(
                    wf[ci], tf[ti], acc[ci][ti], 0, 0, 0);
        // trailing barrier: all waves done reading buf cur before anyone
        // issues tile k+2 into it (mfma's lgkm waits consumed the reads)
        asm volatile("s_barrier" ::: "memory");
    }

    // ---- epilogue: lane owns channels ch0..ch0+3 (contiguous) of one token -
    const int rq   = (lane >> 4) * 4;
    const int chB  = bn * 128 + wn * 64;      // wave channel base
    const int tokB = bm * 128 + wm * 64;      // wave token base

    float4 bias4[4];
    int g0c[4], g3c[4];
#pragma unroll
    for (int ci = 0; ci < 4; ci++) {
        const int ch0 = chB + ci * 16 + rq;
        bias4[ci] = *(const float4*)&bias[ch0];
        if (EPI == 1) { g0c[ci] = ch0 / 114; g3c[ci] = (ch0 + 3) / 114; }
        if (EPI == 2) { g0c[ci] = ch0 / 57;  g3c[ci] = (ch0 + 3) / 57;  }
    }

    float csum[4][4] = {};   // [ci][r] per-channel partial sums (EPI 2,3)

#pragma unroll
    for (int ti = 0; ti < 4; ti++) {
        const int tok = tokB + ti * 16 + ml;
        int ph = 0, pw = 0;
        if (EPI == 1 || EPI == 2) {
            const int bt  = tok / HWIMG;
            const int rem = tok - bt * HWIMG;
            ph = rem / 56;
            pw = rem - ph * 56;
        }
#pragma unroll
        for (int ci = 0; ci < 4; ci++) {
            const int ch0 = chB + ci * 16 + rq;
            float v[4];
#pragma unroll
            for (int r = 0; r < 4; r++) {
                float x = acc[ci][ti][r] + ((const float*)&bias4[ci])[r];
                v[r] = (EPI != 0) ? gelu_fast(x) : x;
            }
            if (EPI == 0) {
                float4 o; o.x = v[0]; o.y = v[1]; o.z = v[2]; o.w = v[3];
                *(float4*)((float*)Cout + (size_t)tok * N + ch0) = o;
            } else {
                const uint u0 = pack_bf2(v[0], v[1]);
                const uint u1 = pack_bf2(v[2], v[3]);
                uint2 uu; uu.x = u0; uu.y = u1;
                *(uint2*)((__hip_bfloat16*)Cout + (size_t)tok * N + ch0) = uu;
                if (EPI == 1) {
                    // forward-shift scatter: xs[tok+s] = xh[tok]
                    if (g0c[ci] == g3c[ci]) {
                        const int sh = shift_h(g0c[ci]), sw = shift_w(g0c[ci]);
                        if ((unsigned)(ph + sh) < 56u && (unsigned)(pw + sw) < 56u)
                            *(uint2*)(Cout2 + (size_t)(tok + sh * 56 + sw) * N + ch0) = uu;
                    } else {
                        // 114 even -> each uint (2ch) uniform
                        const int gA = ch0 / 114, gB = (ch0 + 2) / 114;
                        const int shA = shift_h(gA), swA = shift_w(gA);
                        const int shB = shift_h(gB), swB = shift_w(gB);
                        if ((unsigned)(ph + shA) < 56u && (unsigned)(pw + swA) < 56u)
                            *(uint*)(Cout2 + (size_t)(tok + shA * 56 + swA) * N + ch0) = u0;
                        if ((unsigned)(ph + shB) < 56u && (unsigned)(pw + swB) < 56u)
                            *(uint*)(Cout2 + (size_t)(tok + shB * 56 + swB) * N + ch0 + 2) = u1;
                    }
                } else if (EPI == 2) {
                    // masked sum: hpre[p] counts iff (p - s) is a valid output pos
                    if (g0c[ci] == g3c[ci]) {
                        const int sh = shift_h(g0c[ci]), sw = shift_w(g0c[ci]);
                        if ((unsigned)(ph - sh) < 56u && (unsigned)(pw - sw) < 56u) {
#pragma unroll
                            for (int r = 0; r < 4; r++) csum[ci][r] += v[r];
                        }
                    } else {
#pragma unroll
                        for (int r = 0; r < 4; r++) {
                            const int g = (ch0 + r) / 57;
                            const int sh = shift_h(g), sw = shift_w(g);
                            if ((unsigned)(ph - sh) < 56u && (unsigned)(pw - sw) < 56u)
                                csum[ci][r] += v[r];
                        }
                    }
                } else if (EPI == 3) {
#pragma unroll
                    for (int r = 0; r < 4; r++) csum[ci][r] += v[r];
                }
            }
        }
    }

    if (EPI == 2 || EPI == 3) {
        const int b = (bm >= 196) ? 1 : 0;   // token 25088 = block 196 boundary
#pragma unroll
        for (int ci = 0; ci < 4; ci++) {
#pragma unroll
            for (int r = 0; r < 4; r++) {
                float s = csum[ci][r];
                s += __shfl_xor(s, 1, 64);
                s += __shfl_xor(s, 2, 64);
                s += __shfl_xor(s, 4, 64);
                s += __shfl_xor(s, 8, 64);
                if (ml == 0)
                    atomicAdd(&ssum[b * 512 + chB + ci * 16 + rq + r], s);
            }
        }
    }
}

// ---- zero the shift boundary holes of xs (frame strips only, ~3.5%) --------
template <int C, int GS, int SGN>
__global__ __launch_bounds__(256) void zero_holes(__hip_bfloat16* __restrict__ buf)
{
    const int i = blockIdx.x * 256 + threadIdx.x;   // 16*220*C exact
    const int c = i % C;
    const int p = i / C;
    const int bt = p / 220, fp = p % 220;
    int oh, ow;
    if (fp < 56)       { oh = 0;        ow = fp; }
    else if (fp < 112) { oh = 55;       ow = fp - 56; }
    else if (fp < 166) { oh = fp - 111; ow = 0; }
    else               { oh = fp - 165; ow = 55; }
    const int g = c / GS;
    const int ih = oh - SGN * shift_h(g);
    const int iw = ow - SGN * shift_w(g);
    if ((unsigned)ih >= 56u || (unsigned)iw >= 56u)
        buf[((size_t)(bt * HWIMG + oh * 56 + ow)) * C + c] = __float2bfloat16(0.0f);
}

// ---- prep: x fp32 -> bf16 ---------------------------------------------------
__global__ __launch_bounds__(256) void cvt_x(const float4* __restrict__ x,
                                             __hip_bfloat16* __restrict__ xb)
{
    int i = blockIdx.x * 256 + threadIdx.x;
    float4 v = x[i];
    uint2 o;
    o.x = pack_bf2(v.x, v.y);
    o.y = pack_bf2(v.z, v.w);
    *(uint2*)&xb[(size_t)i * 4] = o;
}

// ---- prep: transpose + convert the 4 weight matrices to bf16 Bt layout -----
__global__ __launch_bounds__(256) void prep_w(
    const float* __restrict__ fcw,  const float* __restrict__ fc1w,
    const float* __restrict__ fc2w, const float* __restrict__ projw,
    __hip_bfloat16* __restrict__ fcwT, __hip_bfloat16* __restrict__ fc1T,
    __hip_bfloat16* __restrict__ fc2T, __hip_bfloat16* __restrict__ projT)
{
    int i = blockIdx.x * 256 + threadIdx.x;
    if (i < 524288) {                       // fc_w [512,1024] -> [1024,512]
        int n = i >> 9, k = i & 511;
        fcwT[i] = __float2bfloat16(fcw[k * 1024 + n]);
    } else if (i < 1048576) {               // fc1_w [1024,512] -> [512,1024]
        int j = i - 524288;
        int n = j >> 10, k = j & 1023;
        fc1T[j] = __float2bfloat16(fc1w[k * 512 + n]);
    } else if (i < 1572864) {               // fc2_w [1024,512] -> [512,1024]
        int j = i - 1048576;
        int n = j >> 10, k = j & 1023;
        fc2T[j] = __float2bfloat16(fc2w[k * 512 + n]);
    } else if (i < 1835008) {               // proj_w [512,512] -> [512,512]
        int j = i - 1572864;
        int n = j >> 9, k = j & 511;
        projT[j] = __float2bfloat16(projw[k * 512 + n]);
    }
}

// ---- tiny squeeze-excite MLP + pairwise softmax, fp32 exact ----------------
__global__ __launch_bounds__(256) void tiny_mlp(
    const float* __restrict__ s0, const float* __restrict__ s1,
    const float* __restrict__ rw1_w, const float* __restrict__ rw1_b,
    const float* __restrict__ rw2_w, const float* __restrict__ rw2_b,
    float* __restrict__ a0, float* __restrict__ a1)
{
    __shared__ float mean[1024];   // [2][512]
    __shared__ float z[256];       // [2][128]
    __shared__ float av[2048];     // [2][1024]
    const int t = threadIdx.x;
    for (int i = t; i < 1024; i += 256)
        mean[i] = (s0[i] + s1[i]) * (1.0f / 25088.0f);
    __syncthreads();
    {
        const int b = t >> 7, jj = t & 127;
        float acc = rw1_b[jj];
        for (int cc = 0; cc < 512; cc++)
            acc += mean[b * 512 + cc] * rw1_w[cc * 128 + jj];
        z[t] = gelu_exact(acc);
    }
    __syncthreads();
    for (int i = t; i < 2048; i += 256) {
        const int b = i >> 10, o = i & 1023;
        float acc = rw2_b[o];
        for (int jj = 0; jj < 128; jj++)
            acc += z[b * 128 + jj] * rw2_w[jj * 1024 + o];
        av[i] = acc;
    }
    __syncthreads();
    for (int i = t; i < 1024; i += 256) {
        const int b = i >> 9, cc = i & 511;
        const float x0 = av[b * 1024 + 2 * cc];
        const float x1 = av[b * 1024 + 2 * cc + 1];
        const float m = fmaxf(x0, x1);
        const float e0 = expf(x0 - m), e1 = expf(x1 - m);
        const float inv = 1.0f / (e0 + e1);
        a0[i] = e0 * inv;
        a1[i] = e1 * inv;
    }
}

// ---- combine: hw = inv_shift(hpre)*a0 + w*a1 (shift applied on load) -------
__global__ __launch_bounds__(256) void combine(
    const __hip_bfloat16* __restrict__ hpre, const uint4* __restrict__ w4,
    const float* __restrict__ a0, const float* __restrict__ a1,
    uint4* __restrict__ hw4)
{
    const int i = blockIdx.x * 256 + threadIdx.x;   // 3,211,264 exact
    const int ck = i & 63;                          // 8-channel chunk
    const int tok = i >> 6;
    const int b = (tok >= 25088) ? 1 : 0;
    const int c0 = ck * 8;
    const int bt  = tok / HWIMG;
    const int rem = tok - bt * HWIMG;
    const int ph  = rem / 56;
    const int pw  = rem - ph * 56;

    float h[8];
    const int g0 = c0 / 57, g7 = (c0 + 7) / 57;
    if (g0 == g7) {
        const int sh = shift_h(g0), sw = shift_w(g0);
        if ((unsigned)(ph + sh) < 56u && (unsigned)(pw + sw) < 56u) {
            const uint4 hv = *(const uint4*)&hpre[(size_t)(tok + sh * 56 + sw) * 512 + c0];
            h[0] = bf_lo(hv.x); h[1] = bf_hi(hv.x);
            h[2] = bf_lo(hv.y); h[3] = bf_hi(hv.y);
            h[4] = bf_lo(hv.z); h[5] = bf_hi(hv.z);
            h[6] = bf_lo(hv.w); h[7] = bf_hi(hv.w);
        } else {
#pragma unroll
            for (int e = 0; e < 8; e++) h[e] = 0.f;
        }
    } else {
#pragma unroll
        for (int e = 0; e < 8; e++) {
            const int g = (c0 + e) / 57;
            const int sh = shift_h(g), sw = shift_w(g);
            h[e] = ((unsigned)(ph + sh) < 56u && (unsigned)(pw + sw) < 56u)
                 ? (float)hpre[(size_t)(tok + sh * 56 + sw) * 512 + c0 + e] : 0.f;
        }
    }

    const float4* A0 = (const float4*)&a0[b * 512 + c0];
    const float4* A1 = (const float4*)&a1[b * 512 + c0];
    const float4 s0l = A0[0], s0h = A0[1];
    const float4 s1l = A1[0], s1h = A1[1];
    const uint4 w = w4[i];
    uint4 o;
    o.x = pack_bf2(h[0] * s0l.x + bf_lo(w.x) * s1l.x,
                   h[1] * s0l.y + bf_hi(w.x) * s1l.y);
    o.y = pack_bf2(h[2] * s0l.z + bf_lo(w.y) * s1l.z,
                   h[3] * s0l.w + bf_hi(w.y) * s1l.w);
    o.z = pack_bf2(h[4] * s0h.x + bf_lo(w.z) * s1h.x,
                   h[5] * s0h.y + bf_hi(w.z) * s1h.y);
    o.w = pack_bf2(h[6] * s0h.z + bf_lo(w.w) * s1h.z,
                   h[7] * s0h.w + bf_hi(w.w) * s1h.w);
    hw4[i] = o;
}

// ---------------------------------------------------------------------------
extern "C" void kernel_launch(void* const* d_in, const int* in_sizes, int n_in,
                              void* d_out, int out_size, void* d_ws, size_t ws_size,
                              hipStream_t stream)
{
    const float* x      = (const float*)d_in[0];
    const float* fc_w   = (const float*)d_in[1];
    const float* fc_b   = (const float*)d_in[2];
    const float* fc1_w  = (const float*)d_in[3];
    const float* fc1_b  = (const float*)d_in[4];
    const float* fc2_w  = (const float*)d_in[5];
    const float* fc2_b  = (const float*)d_in[6];
    const float* rw1_w  = (const float*)d_in[7];
    const float* rw1_b  = (const float*)d_in[8];
    const float* rw2_w  = (const float*)d_in[9];
    const float* rw2_b  = (const float*)d_in[10];
    const float* proj_w = (const float*)d_in[11];
    const float* proj_b = (const float*)d_in[12];

    uint8_t* ws = (uint8_t*)d_ws;
    __hip_bfloat16* xh  = (__hip_bfloat16*)(ws);                    // [N,1024] bf16, later hw
    __hip_bfloat16* xb  = (__hip_bfloat16*)(ws + 102760448);        // [N,512] bf16, later hpre
    uint8_t* wt         = ws + 102760448 + 51380224;
    __hip_bfloat16* fcwT  = (__hip_bfloat16*)(wt);
    __hip_bfloat16* fc1T  = fcwT + 524288;
    __hip_bfloat16* fc2T  = fc1T + 524288;
    __hip_bfloat16* projT = fc2T + 524288;
    float* s0 = (float*)(wt + 3670016);
    float* s1 = s0 + 1024;
    float* a0 = s1 + 1024;
    float* a1 = a0 + 1024;

    __hip_bfloat16* xs   = (__hip_bfloat16*)d_out;  // [N,1024] bf16 (dead after GEMM2)
    __hip_bfloat16* wbuf = (__hip_bfloat16*)d_out;  // [N,512]  bf16 (dead after combine)
    __hip_bfloat16* hpre = xb;                      // [N,512]  bf16 (xb dead after GEMM1)
    __hip_bfloat16* hw   = xh;                      // [N,512]  bf16 (xh dead after GEMM3)

    hipMemsetAsync(s0, 0, 8192, stream);            // zero s0,s1

    // xs boundary holes (d_out, no deps) — before GEMM1's scatter fills valid cells
    zero_holes<1024, 114, +1><<<14080, 256, 0, stream>>>(xs);
    cvt_x<<<25088, 256, 0, stream>>>((const float4*)x, xb);
    prep_w<<<7168, 256, 0, stream>>>(fc_w, fc1_w, fc2_w, proj_w, fcwT, fc1T, fc2T, projT);

    // GEMM1: xh = gelu(xb@fc_w+b); dual store xh + fwd-shift scatter -> xs
    gemm_bt<1><<<dim3(8, 392), 256, 0, stream>>>(xb, fcwT, fc_b, xh, xs, nullptr, 1024, 512);
    // GEMM2: hpre = gelu(xs@fc1_w+b) plain; fused masked s0
    gemm_bt<2><<<dim3(4, 392), 256, 0, stream>>>(xs, fc1T, fc1_b, hpre, nullptr, s0, 512, 1024);
    // GEMM3: w = gelu(xh@fc2_w+b) -> d_out (xs dead); fused s1
    gemm_bt<3><<<dim3(4, 392), 256, 0, stream>>>(xh, fc2T, fc2_b, wbuf, nullptr, s1, 512, 1024);
    // tiny MLP + softmax -> a0,a1
    tiny_mlp<<<1, 256, 0, stream>>>(s0, s1, rw1_w, rw1_b, rw2_w, rw2_b, a0, a1);
    // hw = inv_shift(hpre)*a0 + w*a1 -> xh region
    combine<<<12544, 256, 0, stream>>>(hpre, (const uint4*)wbuf, a0, a1, (uint4*)hw);
    // GEMM4: out = hw @ proj_w + proj_b, fp32 -> d_out
    gemm_bt<0><<<dim3(4, 392), 256, 0, stream>>>(hw, projT, proj_b, d_out, nullptr, nullptr, 512, 512);
}